// Round 5
// baseline (1407.022 us; speedup 1.0000x reference)
//
#include <hip/hip_runtime.h>
#include <hip/hip_fp16.h>

// N=512, C=3, T=300, V=25, M=2, F=150, H=100, gates=4H=400
// x element (n,c,t,v,m) at n*45000 + c*15000 + t*50 + (v*2+m)
//
// MFMA mapping (16x16x32_f16, HW-verified layouts):
//   A[m][k]: m = lane&15, k = (lane>>4)*8 + j
//   B[k][n]: n = lane&15, k = (lane>>4)*8 + j
//   D[row][col]: col = lane&15, row = (lane>>4)*4 + reg
// Gate tiling: M-tile (w,ty) covers gate rows r = ty*100 + (w*16 + m), w=0..6 (cells padded
// 100->112; rows/cols >=100 zeroed in fragments). i,f,g,o of one cell share lane/reg across ty.

#define B_HIST   0u           // ushort hist[512][29952]
#define HIST_STRIDE 29952
#define B_W2S    30670848u    // float W2[400][100]
#define B_BEFFS  30830848u    // float beff[400]
#define B_AWIH   30832448u    // uint4 [28 mt][5 kc][64 l]   enc Wih frags (K=160 pad)
#define B_AENC   30975808u    // uint4 [28][4][64]           enc Whh frags (K=128 pad)
#define B_ADEC1  31090496u    // uint4 [28][4][64]           dec Whh
#define B_ADEC2  31205184u    // uint4 [28][4][64]           dec W2 = Whh + Wih@fcW
#define B_BENCF  31319872u    // float4 [28][64]             enc bias frags (folded into xg by pre)
#define B_B1F    31348544u    // float4 [28][64]
#define B_BEFFF  31377216u    // float4 [28][64]
#define B_XG     31405888u    // ushort xg[bg][300][7 w][64 l][16]  (D-frag order, enc bias folded)
#define XG_PER_BG 4300800u    // bytes per 16-sample group

typedef _Float16 f16x8 __attribute__((ext_vector_type(8)));
typedef float    f32x4 __attribute__((ext_vector_type(4)));

typedef _Float16 h2_t __attribute__((ext_vector_type(2)));
#if defined(__has_builtin)
#if __has_builtin(__builtin_amdgcn_fdot2)
#define HAS_FDOT2 1
#endif
#endif

__device__ __forceinline__ float fdot2u(unsigned a, unsigned b, float c) {
#ifdef HAS_FDOT2
  return __builtin_amdgcn_fdot2(__builtin_bit_cast(h2_t, a), __builtin_bit_cast(h2_t, b), c, false);
#else
  float al = __half2float(__ushort_as_half((unsigned short)(a & 0xffffu)));
  float ah = __half2float(__ushort_as_half((unsigned short)(a >> 16)));
  float bl = __half2float(__ushort_as_half((unsigned short)(b & 0xffffu)));
  float bh = __half2float(__ushort_as_half((unsigned short)(b >> 16)));
  return fmaf(ah, bh, fmaf(al, bl, c));
#endif
}

__device__ __forceinline__ unsigned pkrtz(float a, float b) {
  return __builtin_bit_cast(unsigned, __builtin_amdgcn_cvt_pkrtz(a, b));
}
__device__ __forceinline__ unsigned pack2f(float a, float b) {
  return (unsigned)__half_as_ushort(__float2half(a)) |
         ((unsigned)__half_as_ushort(__float2half(b)) << 16);
}
__device__ __forceinline__ float fast_sig(float x) {
  float e = __builtin_amdgcn_exp2f(x * -1.442695040888963f);
  return __builtin_amdgcn_rcpf(1.f + e);
}
__device__ __forceinline__ float fast_tanh(float x) {
  float e = __builtin_amdgcn_exp2f(x * -2.885390081777926f);
  return fmaf(2.f, __builtin_amdgcn_rcpf(1.f + e), -1.f);
}
__device__ __forceinline__ f32x4 mfma16(uint4 a, uint4 b, f32x4 c) {
  return __builtin_amdgcn_mfma_f32_16x16x32_f16(
      __builtin_bit_cast(f16x8, a), __builtin_bit_cast(f16x8, b), c, 0, 0, 0);
}
__device__ __forceinline__ float uslo(unsigned u) {
  return __half2float(__ushort_as_half((unsigned short)(u & 0xffffu)));
}
__device__ __forceinline__ float ushi(unsigned u) {
  return __half2float(__ushort_as_half((unsigned short)(u >> 16)));
}

// ---------------- prep_w2: W2 = dWhh + dWih@fcW ; beff = db + dWih@fcb ----------------
__global__ void prep_w2(const float* __restrict__ dWih, const float* __restrict__ dWhh,
                        const float* __restrict__ dbih, const float* __restrict__ dbhh,
                        const float* __restrict__ fcW,  const float* __restrict__ fcb,
                        char* __restrict__ wsb)
{
  int idx = blockIdx.x * 256 + threadIdx.x;
  if (idx < 40000) {
    int r = idx / 100, j = idx - r * 100;
    float s = 0.f;
    for (int f = 0; f < 150; ++f) s = fmaf(dWih[r * 150 + f], fcW[f * 100 + j], s);
    ((float*)(wsb + B_W2S))[idx] = dWhh[r * 100 + j] + s;
  } else if (idx < 40400) {
    int r = idx - 40000;
    float s = 0.f;
    for (int f = 0; f < 150; ++f) s = fmaf(dWih[r * 150 + f], fcb[f], s);
    ((float*)(wsb + B_BEFFS))[r] = dbih[r] + dbhh[r] + s;
  }
}

// ---------------- prep_frags: build A-operand + bias fragments ----------------
__global__ void prep_frags(const float* __restrict__ eWih, const float* __restrict__ eWhh,
                           const float* __restrict__ dWhh,
                           const float* __restrict__ ebih, const float* __restrict__ ebhh,
                           const float* __restrict__ dbih, const float* __restrict__ dbhh,
                           char* __restrict__ wsb)
{
  int idx = blockIdx.x * 256 + threadIdx.x;
  const float* w2s = (const float*)(wsb + B_W2S);
  const float* beffs = (const float*)(wsb + B_BEFFS);
  if (idx < 8960) {                                   // AWIH: [mt][kc(5)][l]
    int l = idx & 63, fi = idx >> 6;
    int kc = fi % 5, mt = fi / 5;
    int w = mt >> 2, ty = mt & 3;
    int gr = w * 16 + (l & 15);
    int r = ty * 100 + gr;
    int k0 = kc * 32 + (l >> 4) * 8;
    unsigned u[4];
    for (int p = 0; p < 4; ++p) {
      int k = k0 + 2 * p;
      float v0 = (gr < 100 && k     < 150) ? eWih[r * 150 + k]     : 0.f;
      float v1 = (gr < 100 && k + 1 < 150) ? eWih[r * 150 + k + 1] : 0.f;
      u[p] = pack2f(v0, v1);
    }
    ((uint4*)(wsb + B_AWIH))[idx] = make_uint4(u[0], u[1], u[2], u[3]);
  } else if (idx < 8960 + 3 * 7168) {                 // h-part A frags, 3 sets
    int t = idx - 8960;
    int set = t / 7168, q = t - set * 7168;
    int l = q & 63, fi = q >> 6;
    int kc = fi & 3, mt = fi >> 2;
    int w = mt >> 2, ty = mt & 3;
    int gr = w * 16 + (l & 15);
    int r = ty * 100 + gr;
    int k0 = kc * 32 + (l >> 4) * 8;
    unsigned u[4];
    for (int p = 0; p < 4; ++p) {
      int k = k0 + 2 * p;
      float v0 = 0.f, v1 = 0.f;
      if (gr < 100) {
        if (k < 100)     v0 = set == 0 ? eWhh[r*100+k]   : set == 1 ? dWhh[r*100+k]   : w2s[r*100+k];
        if (k + 1 < 100) v1 = set == 0 ? eWhh[r*100+k+1] : set == 1 ? dWhh[r*100+k+1] : w2s[r*100+k+1];
      }
      u[p] = pack2f(v0, v1);
    }
    ((uint4*)(wsb + B_AENC + (unsigned)set * 114688u))[q] = make_uint4(u[0], u[1], u[2], u[3]);
  } else if (idx < 8960 + 21504 + 3 * 1792) {         // bias frags (f32x4), 3 sets
    int t = idx - 8960 - 21504;
    int set = t / 1792, q = t - set * 1792;
    int l = q & 63, mt = q >> 6;
    int w = mt >> 2, ty = mt & 3;
    float v[4];
    for (int rr = 0; rr < 4; ++rr) {
      int gr = w * 16 + (l >> 4) * 4 + rr;
      int r = ty * 100 + gr;
      v[rr] = 0.f;
      if (gr < 100)
        v[rr] = set == 0 ? ebih[r] + ebhh[r] : set == 1 ? dbih[r] + dbhh[r] : beffs[r];
    }
    ((float4*)(wsb + B_BENCF + (unsigned)set * 28672u))[q] = make_float4(v[0], v[1], v[2], v[3]);
  }
}

// ---------------- pre: xg = enc bias + Wih @ x_t, written in D-fragment order ----------------
// grid (75 t-groups, bg); 1 wave/block; LDS-staged B = x (f16), A from ws frags.
// NOTE: xls rows are 168 halfs; B-frags read halfs up to 159 -> the staging loop below
// initializes ALL 168 halfs (pairs p>=75 zeroed). R4's NaN came from 0 x uninit-LDS here.
__global__ __launch_bounds__(64)
void pre(const float* __restrict__ x, char* __restrict__ wsb, int nbase)
{
  const int l = threadIdx.x;
  const int tg = blockIdx.x;      // 0..74 -> t0 = 4*tg
  const int b  = blockIdx.y;      // local sample group
  const int quad = l >> 4, nn = l & 15;
  __shared__ unsigned short xls[4][16][168];

  const int t0 = tg * 4;
  const int n0 = nbase + b * 16;
  // stage 4 timesteps x 16 samples x 84 f16-pairs (75 real, 9 zero pad)
  for (int it = 0; it < 84; ++it) {
    int i = l + it * 64;
    int tp = i / 1344; int rem = i - tp * 1344;
    int np = rem / 84; int p = rem - np * 84;
    unsigned val = 0;
    if (p < 75) {
      int f0 = 2 * p; int c = f0 / 50; int q = f0 - c * 50;
      const float2 v = *(const float2*)(x + (size_t)(n0 + np) * 45000 + c * 15000 + (t0 + tp) * 50 + q);
      val = pkrtz(v.x, v.y);
    }
    *(unsigned*)&xls[tp][np][2 * p] = val;
  }
  __syncthreads();

  uint4 B[4][5];
#pragma unroll
  for (int u = 0; u < 4; ++u)
#pragma unroll
    for (int kc = 0; kc < 5; ++kc)
      B[u][kc] = *(const uint4*)&xls[u][nn][kc * 32 + quad * 8];

  const uint4* awih = (const uint4*)(wsb + B_AWIH);
  const float4* bencf = (const float4*)(wsb + B_BENCF);
  unsigned short* xgo = (unsigned short*)(wsb + B_XG);

  for (int mt = 0; mt < 28; ++mt) {
    const int w = mt >> 2, ty = mt & 3;
    uint4 A0 = awih[(mt * 5 + 0) * 64 + l];
    uint4 A1 = awih[(mt * 5 + 1) * 64 + l];
    uint4 A2 = awih[(mt * 5 + 2) * 64 + l];
    uint4 A3 = awih[(mt * 5 + 3) * 64 + l];
    uint4 A4 = awih[(mt * 5 + 4) * 64 + l];
    float4 bi = bencf[mt * 64 + l];
    f32x4 bias; bias[0] = bi.x; bias[1] = bi.y; bias[2] = bi.z; bias[3] = bi.w;
#pragma unroll
    for (int u = 0; u < 4; ++u) {
      f32x4 acc = bias;
      acc = mfma16(A0, B[u][0], acc);
      acc = mfma16(A1, B[u][1], acc);
      acc = mfma16(A2, B[u][2], acc);
      acc = mfma16(A3, B[u][3], acc);
      acc = mfma16(A4, B[u][4], acc);
      unsigned u0 = pkrtz(acc[0], acc[1]);
      unsigned u1 = pkrtz(acc[2], acc[3]);
      size_t off = ((size_t)(b * 300 + t0 + u) * 7 + w) * 1024 + l * 16 + ty * 4;
      *(uint2*)(xgo + off) = make_uint2(u0, u1);
    }
  }
}

// ---------------- recurrent: 599 serial steps, MFMA per step ----------------
__global__ __launch_bounds__(448)
void recurrent(char* __restrict__ wsb, int nbase)
{
  const int tid = threadIdx.x;
  const int l = tid & 63, w = tid >> 6;          // wave = cell-tile
  const int quad = l >> 4, n = l & 15;
  const int c0 = w * 16 + quad * 4;
  __shared__ unsigned short hbuf[2][16][136];

  for (int i = tid; i < 2176; i += 448) ((unsigned*)hbuf)[i] = 0;

  const uint4* aenc  = (const uint4*)(wsb + B_AENC);
  const uint4* adec1 = (const uint4*)(wsb + B_ADEC1);
  const uint4* adec2 = (const uint4*)(wsb + B_ADEC2);
  uint4 A[4][4];
#pragma unroll
  for (int ty = 0; ty < 4; ++ty)
#pragma unroll
    for (int kc = 0; kc < 4; ++kc)
      A[ty][kc] = aenc[((w * 4 + ty) * 4 + kc) * 64 + l];

  f32x4 bias[4];
  float cst[4] = {0.f, 0.f, 0.f, 0.f};

  const uint4* xgw = (const uint4*)(wsb + B_XG) + (size_t)blockIdx.x * 300 * 896 + (w * 64 + l) * 2;
  uint4 xa = xgw[0], xb = xgw[1];

  unsigned short* hist = (unsigned short*)(wsb + B_HIST) +
                         (size_t)(nbase + blockIdx.x * 16 + n) * HIST_STRIDE + c0;
  const bool hist_on = (c0 < 100);

  for (int g = 0; g < 599; ++g) {
    __syncthreads();
    const int rd = g & 1, wr = rd ^ 1;
    uint4 B0 = *(const uint4*)&hbuf[rd][n][0  + quad * 8];
    uint4 B1 = *(const uint4*)&hbuf[rd][n][32 + quad * 8];
    uint4 B2 = *(const uint4*)&hbuf[rd][n][64 + quad * 8];
    uint4 B3 = *(const uint4*)&hbuf[rd][n][96 + quad * 8];

    f32x4 acc[4];
    if (g < 300) {
      acc[0][0] = uslo(xa.x); acc[0][1] = ushi(xa.x); acc[0][2] = uslo(xa.y); acc[0][3] = ushi(xa.y);
      acc[1][0] = uslo(xa.z); acc[1][1] = ushi(xa.z); acc[1][2] = uslo(xa.w); acc[1][3] = ushi(xa.w);
      acc[2][0] = uslo(xb.x); acc[2][1] = ushi(xb.x); acc[2][2] = uslo(xb.y); acc[2][3] = ushi(xb.y);
      acc[3][0] = uslo(xb.z); acc[3][1] = ushi(xb.z); acc[3][2] = uslo(xb.w); acc[3][3] = ushi(xb.w);
      if (g < 299) { const uint4* p = xgw + (size_t)(g + 1) * 896; xa = p[0]; xb = p[1]; }
    } else {
#pragma unroll
      for (int ty = 0; ty < 4; ++ty) acc[ty] = bias[ty];
    }

#pragma unroll
    for (int kc = 0; kc < 4; ++kc) {
      uint4 Bk = (kc == 0) ? B0 : (kc == 1) ? B1 : (kc == 2) ? B2 : B3;
#pragma unroll
      for (int ty = 0; ty < 4; ++ty) acc[ty] = mfma16(A[ty][kc], Bk, acc[ty]);
    }

    float hv[4];
#pragma unroll
    for (int r = 0; r < 4; ++r) {
      float si = fast_sig(acc[0][r]);
      float sf = fast_sig(acc[1][r]);
      float tg = fast_tanh(acc[2][r]);
      float so = fast_sig(acc[3][r]);
      cst[r] = fmaf(sf, cst[r], si * tg);
      hv[r] = so * fast_tanh(cst[r]);
    }
    unsigned u0 = pkrtz(hv[0], hv[1]);
    unsigned u1 = pkrtz(hv[2], hv[3]);
    *(uint2*)&hbuf[wr][n][c0] = make_uint2(u0, u1);
    if (g >= 300 && hist_on)
      *(uint2*)(hist + (size_t)(g - 300) * 100) = make_uint2(u0, u1);

    if (g == 299) {
#pragma unroll
      for (int ty = 0; ty < 4; ++ty) {
#pragma unroll
        for (int kc = 0; kc < 4; ++kc) A[ty][kc] = adec1[((w * 4 + ty) * 4 + kc) * 64 + l];
        float4 bv = ((const float4*)(wsb + B_B1F))[(w * 4 + ty) * 64 + l];
        bias[ty][0] = bv.x; bias[ty][1] = bv.y; bias[ty][2] = bv.z; bias[ty][3] = bv.w;
      }
    } else if (g == 300) {
#pragma unroll
      for (int ty = 0; ty < 4; ++ty) {
#pragma unroll
        for (int kc = 0; kc < 4; ++kc) A[ty][kc] = adec2[((w * 4 + ty) * 4 + kc) * 64 + l];
        float4 bv = ((const float4*)(wsb + B_BEFFF))[(w * 4 + ty) * 64 + l];
        bias[ty][0] = bv.x; bias[ty][1] = bv.y; bias[ty][2] = bv.z; bias[ty][3] = bv.w;
      }
    }
  }
}

// ---------------- emit: out[n][t] = fcW @ h_{t-1} + fcb (unchanged, known-correct) ----------------
__global__ __launch_bounds__(192, 4)
void emit(const char* __restrict__ wsb, const float* __restrict__ fcW,
          const float* __restrict__ fcb, float* __restrict__ out)
{
  const int f = threadIdx.x;
  const int n = blockIdx.x;
  const int z = blockIdx.y;
  __shared__ unsigned short hl[15008];

  const uint4* src = (const uint4*)((const unsigned short*)(wsb + B_HIST) +
                                    (size_t)n * HIST_STRIDE + z * 15000);
  for (int k = f; k < 1875; k += 192) ((uint4*)hl)[k] = src[k];

  const bool on = f < 150;
  unsigned fw[50];
  float biasv = 0.f;
  if (on) {
    const float* fp = fcW + f * 100;
#pragma unroll
    for (int q = 0; q < 50; ++q) fw[q] = pack2f(fp[2 * q], fp[2 * q + 1]);
    biasv = fcb[f];
  }
  __syncthreads();

  if (!on) return;
  const int cc = f / 50, r = f - cc * 50;
  float* ob = out + (size_t)n * 45000 + cc * 15000 + r;
  if (z == 0) ob[0] = 0.f;
  const int rows = z ? 149 : 150;
  for (int tl = 0; tl < rows; ++tl) {
    const uint4* row = (const uint4*)(hl + tl * 100);
    float a0 = biasv, a1 = 0.f, a2 = 0.f, a3 = 0.f;
#pragma unroll
    for (int ch = 0; ch < 12; ++ch) {
      uint4 v = row[ch];
      a0 = fdot2u(fw[4 * ch + 0], v.x, a0);
      a1 = fdot2u(fw[4 * ch + 1], v.y, a1);
      a2 = fdot2u(fw[4 * ch + 2], v.z, a2);
      a3 = fdot2u(fw[4 * ch + 3], v.w, a3);
    }
    uint2 v2 = *(const uint2*)(hl + tl * 100 + 96);
    a0 = fdot2u(fw[48], v2.x, a0);
    a1 = fdot2u(fw[49], v2.y, a1);
    const int tt = z * 150 + tl + 1;
    ob[tt * 50] = (a0 + a1) + (a2 + a3);
  }
}

extern "C" void kernel_launch(void* const* d_in, const int* in_sizes, int n_in,
                              void* d_out, int out_size, void* d_ws, size_t ws_size,
                              hipStream_t stream) {
  const float* x    = (const float*)d_in[0];
  const float* eWih = (const float*)d_in[1];
  const float* eWhh = (const float*)d_in[2];
  const float* ebih = (const float*)d_in[3];
  const float* ebhh = (const float*)d_in[4];
  const float* dWih = (const float*)d_in[5];
  const float* dWhh = (const float*)d_in[6];
  const float* dbih = (const float*)d_in[7];
  const float* dbhh = (const float*)d_in[8];
  const float* fcW  = (const float*)d_in[9];
  const float* fcb  = (const float*)d_in[10];
  float* out = (float*)d_out;
  char* wsb  = (char*)d_ws;

  int npass = 1;
  while (npass < 32) {
    if ((size_t)B_XG + (size_t)(32 / npass) * XG_PER_BG <= ws_size) break;
    npass *= 2;
  }
  const int bg = 32 / npass;

  prep_w2<<<158, 256, 0, stream>>>(dWih, dWhh, dbih, dbhh, fcW, fcb, wsb);
  prep_frags<<<140, 256, 0, stream>>>(eWih, eWhh, dWhh, ebih, ebhh, dbih, dbhh, wsb);
  for (int p = 0; p < npass; ++p) {
    pre<<<dim3(75, bg), 64, 0, stream>>>(x, wsb, p * bg * 16);
    recurrent<<<bg, 448, 0, stream>>>(wsb, p * bg * 16);
  }
  emit<<<dim3(512, 2), 192, 0, stream>>>(wsb, fcW, fcb, out);
}

// Round 6
// 1188.758 us; speedup vs baseline: 1.1836x; 1.1836x over previous
//
#include <hip/hip_runtime.h>
#include <hip/hip_fp16.h>

// N=512, C=3, T=300, V=25, M=2, F=150, H=100, gates=4H=400
// x element (n,c,t,v,m) at n*45000 + c*15000 + t*50 + (v*2+m)
//
// MFMA mapping (16x16x32_f16, HW-verified layouts):
//   A[m][k]: m = lane&15, k = (lane>>4)*8 + j
//   B[k][n]: n = lane&15, k = (lane>>4)*8 + j
//   D[row][col]: col = lane&15, row = (lane>>4)*4 + reg
// Gate tiling: M-tile (w,ty) covers gate rows r = ty*100 + (w*16 + m), w=0..6.

#define B_HIST   0u           // ushort hist[512][29952]
#define HIST_STRIDE 29952
#define B_W2S    30670848u    // float W2[400][100]
#define B_BEFFS  30830848u    // float beff[400]
#define B_AWIH   30832448u    // uint4 [28 mt][5 kc][64 l]   enc Wih frags (K=160 pad)
#define B_AENC   30975808u    // uint4 [28][4][64]           enc Whh frags (K=128 pad)
#define B_ADEC1  31090496u    // uint4 [28][4][64]           dec Whh
#define B_ADEC2  31205184u    // uint4 [28][4][64]           dec W2 = Whh + Wih@fcW
#define B_BENCF  31319872u    // float4 [28][64]             enc bias frags
#define B_B1F    31348544u    // float4 [28][64]
#define B_BEFFF  31377216u    // float4 [28][64]
#define B_AFCW   31405888u    // uint4 [10 mt][4 kc][64]     fcW frags for emit (M=160,K=128 pad)
#define B_XG     31446848u    // ushort xg[bg][300][7 w][64 l][16]  (D-frag order, enc bias folded)
#define XG_PER_BG 4300800u    // bytes per 16-sample group

typedef _Float16 f16x8 __attribute__((ext_vector_type(8)));
typedef float    f32x4 __attribute__((ext_vector_type(4)));

// LDS-only barrier: no vmcnt(0) drain -> global prefetch/stores float across steps.
#define WG_BARRIER() asm volatile("s_waitcnt lgkmcnt(0)\n\ts_barrier" ::: "memory")

__device__ __forceinline__ unsigned pkrtz(float a, float b) {
  return __builtin_bit_cast(unsigned, __builtin_amdgcn_cvt_pkrtz(a, b));
}
__device__ __forceinline__ unsigned pack2f(float a, float b) {
  return (unsigned)__half_as_ushort(__float2half(a)) |
         ((unsigned)__half_as_ushort(__float2half(b)) << 16);
}
__device__ __forceinline__ float fast_sig(float x) {
  float e = __builtin_amdgcn_exp2f(x * -1.442695040888963f);
  return __builtin_amdgcn_rcpf(1.f + e);
}
__device__ __forceinline__ float fast_tanh(float x) {
  float e = __builtin_amdgcn_exp2f(x * -2.885390081777926f);
  return fmaf(2.f, __builtin_amdgcn_rcpf(1.f + e), -1.f);
}
__device__ __forceinline__ f32x4 mfma16(uint4 a, uint4 b, f32x4 c) {
  return __builtin_amdgcn_mfma_f32_16x16x32_f16(
      __builtin_bit_cast(f16x8, a), __builtin_bit_cast(f16x8, b), c, 0, 0, 0);
}
__device__ __forceinline__ float uslo(unsigned u) {
  return __half2float(__ushort_as_half((unsigned short)(u & 0xffffu)));
}
__device__ __forceinline__ float ushi(unsigned u) {
  return __half2float(__ushort_as_half((unsigned short)(u >> 16)));
}

// ---------------- prep_w2: W2 = dWhh + dWih@fcW ; beff = db + dWih@fcb ----------------
__global__ void prep_w2(const float* __restrict__ dWih, const float* __restrict__ dWhh,
                        const float* __restrict__ dbih, const float* __restrict__ dbhh,
                        const float* __restrict__ fcW,  const float* __restrict__ fcb,
                        char* __restrict__ wsb)
{
  int idx = blockIdx.x * 256 + threadIdx.x;
  if (idx < 40000) {
    int r = idx / 100, j = idx - r * 100;
    float s = 0.f;
    for (int f = 0; f < 150; ++f) s = fmaf(dWih[r * 150 + f], fcW[f * 100 + j], s);
    ((float*)(wsb + B_W2S))[idx] = dWhh[r * 100 + j] + s;
  } else if (idx < 40400) {
    int r = idx - 40000;
    float s = 0.f;
    for (int f = 0; f < 150; ++f) s = fmaf(dWih[r * 150 + f], fcb[f], s);
    ((float*)(wsb + B_BEFFS))[r] = dbih[r] + dbhh[r] + s;
  }
}

// ---------------- prep_frags: build A-operand + bias fragments ----------------
__global__ void prep_frags(const float* __restrict__ eWih, const float* __restrict__ eWhh,
                           const float* __restrict__ dWhh, const float* __restrict__ fcW,
                           const float* __restrict__ ebih, const float* __restrict__ ebhh,
                           const float* __restrict__ dbih, const float* __restrict__ dbhh,
                           char* __restrict__ wsb)
{
  int idx = blockIdx.x * 256 + threadIdx.x;
  const float* w2s = (const float*)(wsb + B_W2S);
  const float* beffs = (const float*)(wsb + B_BEFFS);
  if (idx < 8960) {                                   // AWIH: [mt][kc(5)][l]
    int l = idx & 63, fi = idx >> 6;
    int kc = fi % 5, mt = fi / 5;
    int w = mt >> 2, ty = mt & 3;
    int gr = w * 16 + (l & 15);
    int r = ty * 100 + gr;
    int k0 = kc * 32 + (l >> 4) * 8;
    unsigned u[4];
    for (int p = 0; p < 4; ++p) {
      int k = k0 + 2 * p;
      float v0 = (gr < 100 && k     < 150) ? eWih[r * 150 + k]     : 0.f;
      float v1 = (gr < 100 && k + 1 < 150) ? eWih[r * 150 + k + 1] : 0.f;
      u[p] = pack2f(v0, v1);
    }
    ((uint4*)(wsb + B_AWIH))[idx] = make_uint4(u[0], u[1], u[2], u[3]);
  } else if (idx < 8960 + 3 * 7168) {                 // h-part A frags, 3 sets
    int t = idx - 8960;
    int set = t / 7168, q = t - set * 7168;
    int l = q & 63, fi = q >> 6;
    int kc = fi & 3, mt = fi >> 2;
    int w = mt >> 2, ty = mt & 3;
    int gr = w * 16 + (l & 15);
    int r = ty * 100 + gr;
    int k0 = kc * 32 + (l >> 4) * 8;
    unsigned u[4];
    for (int p = 0; p < 4; ++p) {
      int k = k0 + 2 * p;
      float v0 = 0.f, v1 = 0.f;
      if (gr < 100) {
        if (k < 100)     v0 = set == 0 ? eWhh[r*100+k]   : set == 1 ? dWhh[r*100+k]   : w2s[r*100+k];
        if (k + 1 < 100) v1 = set == 0 ? eWhh[r*100+k+1] : set == 1 ? dWhh[r*100+k+1] : w2s[r*100+k+1];
      }
      u[p] = pack2f(v0, v1);
    }
    ((uint4*)(wsb + B_AENC + (unsigned)set * 114688u))[q] = make_uint4(u[0], u[1], u[2], u[3]);
  } else if (idx < 8960 + 21504 + 3 * 1792) {         // bias frags (f32x4), 3 sets
    int t = idx - 8960 - 21504;
    int set = t / 1792, q = t - set * 1792;
    int l = q & 63, mt = q >> 6;
    int w = mt >> 2, ty = mt & 3;
    float v[4];
    for (int rr = 0; rr < 4; ++rr) {
      int gr = w * 16 + (l >> 4) * 4 + rr;
      int r = ty * 100 + gr;
      v[rr] = 0.f;
      if (gr < 100)
        v[rr] = set == 0 ? ebih[r] + ebhh[r] : set == 1 ? dbih[r] + dbhh[r] : beffs[r];
    }
    ((float4*)(wsb + B_BENCF + (unsigned)set * 28672u))[q] = make_float4(v[0], v[1], v[2], v[3]);
  } else if (idx < 35840 + 2560) {                    // AFCW: fcW frags for emit
    int q2 = idx - 35840;
    int l = q2 & 63, fi = q2 >> 6;                    // fi 0..39
    int kc = fi & 3, mt = fi >> 2;
    int f = mt * 16 + (l & 15);
    int k0 = kc * 32 + (l >> 4) * 8;
    unsigned u[4];
    for (int p = 0; p < 4; ++p) {
      int k = k0 + 2 * p;
      float v0 = (f < 150 && k     < 100) ? fcW[f * 100 + k]     : 0.f;
      float v1 = (f < 150 && k + 1 < 100) ? fcW[f * 100 + k + 1] : 0.f;
      u[p] = pack2f(v0, v1);
    }
    ((uint4*)(wsb + B_AFCW))[q2] = make_uint4(u[0], u[1], u[2], u[3]);
  }
}

// ---------------- pre: xg = enc bias + Wih @ x_t, D-fragment order, coalesced stores -------
__global__ __launch_bounds__(64)
void pre(const float* __restrict__ x, char* __restrict__ wsb, int nbase)
{
  const int l = threadIdx.x;
  const int tg = blockIdx.x;      // 0..74 -> t0 = 4*tg
  const int b  = blockIdx.y;      // local sample group
  const int quad = l >> 4, nn = l & 15;
  __shared__ unsigned short xls[4][16][168];

  const int t0 = tg * 4;
  const int n0 = nbase + b * 16;
  // stage 4 timesteps x 16 samples x 84 f16-pairs (75 real, 9 zero pad; ALL halfs initialized)
  for (int it = 0; it < 84; ++it) {
    int i = l + it * 64;
    int tp = i / 1344; int rem = i - tp * 1344;
    int np = rem / 84; int p = rem - np * 84;
    unsigned val = 0;
    if (p < 75) {
      int c = p * 2 / 50; int q = p * 2 - c * 50;
      const float2 v = *(const float2*)(x + (size_t)(n0 + np) * 45000 + c * 15000 + (t0 + tp) * 50 + q);
      val = pkrtz(v.x, v.y);
    }
    *(unsigned*)&xls[tp][np][2 * p] = val;
  }
  __syncthreads();

  uint4 B[4][5];
#pragma unroll
  for (int u = 0; u < 4; ++u)
#pragma unroll
    for (int kc = 0; kc < 5; ++kc)
      B[u][kc] = *(const uint4*)&xls[u][nn][kc * 32 + quad * 8];

  const uint4* awih = (const uint4*)(wsb + B_AWIH);
  const float4* bencf = (const float4*)(wsb + B_BENCF);
  unsigned short* xgo = (unsigned short*)(wsb + B_XG);

  for (int w = 0; w < 7; ++w) {
    unsigned st[4][8];   // [u][ty*2+half]
#pragma unroll
    for (int ty = 0; ty < 4; ++ty) {
      const int mt = w * 4 + ty;
      uint4 A0 = awih[(mt * 5 + 0) * 64 + l];
      uint4 A1 = awih[(mt * 5 + 1) * 64 + l];
      uint4 A2 = awih[(mt * 5 + 2) * 64 + l];
      uint4 A3 = awih[(mt * 5 + 3) * 64 + l];
      uint4 A4 = awih[(mt * 5 + 4) * 64 + l];
      float4 bi = bencf[mt * 64 + l];
      f32x4 bias; bias[0] = bi.x; bias[1] = bi.y; bias[2] = bi.z; bias[3] = bi.w;
#pragma unroll
      for (int u = 0; u < 4; ++u) {
        f32x4 acc = bias;
        acc = mfma16(A0, B[u][0], acc);
        acc = mfma16(A1, B[u][1], acc);
        acc = mfma16(A2, B[u][2], acc);
        acc = mfma16(A3, B[u][3], acc);
        acc = mfma16(A4, B[u][4], acc);
        st[u][ty * 2 + 0] = pkrtz(acc[0], acc[1]);
        st[u][ty * 2 + 1] = pkrtz(acc[2], acc[3]);
      }
    }
#pragma unroll
    for (int u = 0; u < 4; ++u) {
      size_t off = ((size_t)(b * 300 + t0 + u) * 7 + w) * 1024 + (size_t)l * 16;
      *(uint4*)(xgo + off)     = make_uint4(st[u][0], st[u][1], st[u][2], st[u][3]);
      *(uint4*)(xgo + off + 8) = make_uint4(st[u][4], st[u][5], st[u][6], st[u][7]);
    }
  }
}

// ---------------- recurrent: 599 serial steps, MFMA + LDS-only barrier ----------------
__global__ __launch_bounds__(448)
void recurrent(char* __restrict__ wsb, int nbase)
{
  const int tid = threadIdx.x;
  const int l = tid & 63, w = tid >> 6;          // wave = cell-tile
  const int quad = l >> 4, n = l & 15;
  const int c0 = w * 16 + quad * 4;
  __shared__ unsigned short hbuf[2][16][136];

  for (int i = tid; i < 2176; i += 448) ((unsigned*)hbuf)[i] = 0;

  const uint4* aenc  = (const uint4*)(wsb + B_AENC);
  const uint4* adec1 = (const uint4*)(wsb + B_ADEC1);
  const uint4* adec2 = (const uint4*)(wsb + B_ADEC2);
  uint4 A[4][4];
#pragma unroll
  for (int ty = 0; ty < 4; ++ty)
#pragma unroll
    for (int kc = 0; kc < 4; ++kc)
      A[ty][kc] = aenc[((w * 4 + ty) * 4 + kc) * 64 + l];

  f32x4 bias[4];
  float cst[4] = {0.f, 0.f, 0.f, 0.f};

  const uint4* xgw = (const uint4*)(wsb + B_XG) + (size_t)blockIdx.x * 300 * 896 + (w * 64 + l) * 2;
  uint4 pxa[2], pxb[2];                 // 2-step-deep xg prefetch
  pxa[0] = xgw[0];   pxb[0] = xgw[1];
  pxa[1] = xgw[896]; pxb[1] = xgw[897];

  unsigned short* hist = (unsigned short*)(wsb + B_HIST) +
                         (size_t)(nbase + blockIdx.x * 16 + n) * HIST_STRIDE + c0;
  const bool hist_on = (c0 < 100);

  for (int g = 0; g < 599; ++g) {
    WG_BARRIER();
    const int rd = g & 1, wr = rd ^ 1;
    uint4 B0 = *(const uint4*)&hbuf[rd][n][0  + quad * 8];
    uint4 B1 = *(const uint4*)&hbuf[rd][n][32 + quad * 8];
    uint4 B2 = *(const uint4*)&hbuf[rd][n][64 + quad * 8];
    uint4 B3 = *(const uint4*)&hbuf[rd][n][96 + quad * 8];

    f32x4 acc[4];
    if (g < 300) {
      const int sl = g & 1;
      uint4 xa = pxa[sl], xb = pxb[sl];
      acc[0][0] = uslo(xa.x); acc[0][1] = ushi(xa.x); acc[0][2] = uslo(xa.y); acc[0][3] = ushi(xa.y);
      acc[1][0] = uslo(xa.z); acc[1][1] = ushi(xa.z); acc[1][2] = uslo(xa.w); acc[1][3] = ushi(xa.w);
      acc[2][0] = uslo(xb.x); acc[2][1] = ushi(xb.x); acc[2][2] = uslo(xb.y); acc[2][3] = ushi(xb.y);
      acc[3][0] = uslo(xb.z); acc[3][1] = ushi(xb.z); acc[3][2] = uslo(xb.w); acc[3][3] = ushi(xb.w);
      if (g + 2 < 300) { const uint4* p = xgw + (size_t)(g + 2) * 896; pxa[sl] = p[0]; pxb[sl] = p[1]; }
    } else {
#pragma unroll
      for (int ty = 0; ty < 4; ++ty) acc[ty] = bias[ty];
    }

#pragma unroll
    for (int kc = 0; kc < 4; ++kc) {
      uint4 Bk = (kc == 0) ? B0 : (kc == 1) ? B1 : (kc == 2) ? B2 : B3;
#pragma unroll
      for (int ty = 0; ty < 4; ++ty) acc[ty] = mfma16(A[ty][kc], Bk, acc[ty]);
    }

    float hv[4];
#pragma unroll
    for (int r = 0; r < 4; ++r) {
      float si = fast_sig(acc[0][r]);
      float sf = fast_sig(acc[1][r]);
      float tg = fast_tanh(acc[2][r]);
      float so = fast_sig(acc[3][r]);
      cst[r] = fmaf(sf, cst[r], si * tg);
      hv[r] = so * fast_tanh(cst[r]);
    }
    unsigned u0 = pkrtz(hv[0], hv[1]);
    unsigned u1 = pkrtz(hv[2], hv[3]);
    *(uint2*)&hbuf[wr][n][c0] = make_uint2(u0, u1);
    if (g >= 300 && hist_on)
      *(uint2*)(hist + (size_t)(g - 300) * 100) = make_uint2(u0, u1);

    if (g == 299) {
#pragma unroll
      for (int ty = 0; ty < 4; ++ty) {
#pragma unroll
        for (int kc = 0; kc < 4; ++kc) A[ty][kc] = adec1[((w * 4 + ty) * 4 + kc) * 64 + l];
        float4 bv = ((const float4*)(wsb + B_B1F))[(w * 4 + ty) * 64 + l];
        bias[ty][0] = bv.x; bias[ty][1] = bv.y; bias[ty][2] = bv.z; bias[ty][3] = bv.w;
      }
    } else if (g == 300) {
#pragma unroll
      for (int ty = 0; ty < 4; ++ty) {
#pragma unroll
        for (int kc = 0; kc < 4; ++kc) A[ty][kc] = adec2[((w * 4 + ty) * 4 + kc) * 64 + l];
        float4 bv = ((const float4*)(wsb + B_BEFFF))[(w * 4 + ty) * 64 + l];
        bias[ty][0] = bv.x; bias[ty][1] = bv.y; bias[ty][2] = bv.z; bias[ty][3] = bv.w;
      }
    }
  }
}

// ---------------- emit: out[n][t] = fcW @ h_{t-1} + fcb via MFMA; 1 wave per sample --------
// M=fcW rows (150->160 pad, 10 mt), N=output t (16 per tile), K=100->128 pad.
// Cols with t>299 read garbage-but-allocated hist and are never stored (MFMA cols independent).
__global__ __launch_bounds__(64)
void emit(const char* __restrict__ wsb, const float* __restrict__ fcb, float* __restrict__ out)
{
  const int l = threadIdx.x;
  const int n = blockIdx.x;
  const int quad = l >> 4, col = l & 15;
  const uint4* afcw = (const uint4*)(wsb + B_AFCW);
  const unsigned short* hist_n = (const unsigned short*)(wsb + B_HIST) + (size_t)n * HIST_STRIDE;
  float* on_ = out + (size_t)n * 45000;

  // t=0 slice is defined zero
  for (int i = l; i < 150; i += 64) on_[(i / 50) * 15000 + (i % 50)] = 0.f;

  uint4 A[10][4];
#pragma unroll
  for (int mt = 0; mt < 10; ++mt)
#pragma unroll
    for (int kc = 0; kc < 4; ++kc)
      A[mt][kc] = afcw[(mt * 4 + kc) * 64 + l];

  float fcbv[10][4];
#pragma unroll
  for (int mt = 0; mt < 10; ++mt)
#pragma unroll
    for (int r = 0; r < 4; ++r) {
      int f = mt * 16 + quad * 4 + r;
      fcbv[mt][r] = (f < 150) ? fcb[f] : 0.f;
    }

  for (int tt = 0; tt < 19; ++tt) {
    const int t0 = 1 + tt * 16;
    const int th = t0 + col - 1;                       // hist row for this lane's column
    const unsigned short* hb = hist_n + (size_t)th * 100 + quad * 8;
    uint4 B0 = *(const uint4*)(hb);
    uint4 B1 = *(const uint4*)(hb + 32);
    uint4 B2 = *(const uint4*)(hb + 64);
    uint4 B3 = *(const uint4*)(hb + 96);
    const int t = t0 + col;
    const bool ton = (t <= 299);
#pragma unroll
    for (int mt = 0; mt < 10; ++mt) {
      f32x4 acc;
      acc[0] = fcbv[mt][0]; acc[1] = fcbv[mt][1]; acc[2] = fcbv[mt][2]; acc[3] = fcbv[mt][3];
      acc = mfma16(A[mt][0], B0, acc);
      acc = mfma16(A[mt][1], B1, acc);
      acc = mfma16(A[mt][2], B2, acc);
      acc = mfma16(A[mt][3], B3, acc);
#pragma unroll
      for (int r = 0; r < 4; ++r) {
        const int f = mt * 16 + quad * 4 + r;
        if (ton && f < 150) {
          const int c = f / 50, vm = f - c * 50;
          on_[c * 15000 + t * 50 + vm] = acc[r];
        }
      }
    }
  }
}

extern "C" void kernel_launch(void* const* d_in, const int* in_sizes, int n_in,
                              void* d_out, int out_size, void* d_ws, size_t ws_size,
                              hipStream_t stream) {
  const float* x    = (const float*)d_in[0];
  const float* eWih = (const float*)d_in[1];
  const float* eWhh = (const float*)d_in[2];
  const float* ebih = (const float*)d_in[3];
  const float* ebhh = (const float*)d_in[4];
  const float* dWih = (const float*)d_in[5];
  const float* dWhh = (const float*)d_in[6];
  const float* dbih = (const float*)d_in[7];
  const float* dbhh = (const float*)d_in[8];
  const float* fcW  = (const float*)d_in[9];
  const float* fcb  = (const float*)d_in[10];
  float* out = (float*)d_out;
  char* wsb  = (char*)d_ws;

  int npass = 1;
  while (npass < 32) {
    if ((size_t)B_XG + (size_t)(32 / npass) * XG_PER_BG <= ws_size) break;
    npass *= 2;
  }
  const int bg = 32 / npass;

  prep_w2<<<158, 256, 0, stream>>>(dWih, dWhh, dbih, dbhh, fcW, fcb, wsb);
  prep_frags<<<150, 256, 0, stream>>>(eWih, eWhh, dWhh, fcW, ebih, ebhh, dbih, dbhh, wsb);
  for (int p = 0; p < npass; ++p) {
    pre<<<dim3(75, bg), 64, 0, stream>>>(x, wsb, p * bg * 16);
    recurrent<<<bg, 448, 0, stream>>>(wsb, p * bg * 16);
  }
  emit<<<512, 64, 0, stream>>>(wsb, fcb, out);
}